// Round 5
// baseline (186.594 us; speedup 1.0000x reference)
//
#include <hip/hip_runtime.h>
#include <stdint.h>

#define M_DIM 2048
#define K_DIM 4096
#define N_DIM 11008

typedef int v4i __attribute__((ext_vector_type(4)));

// ---------------- workspace layout ----------------
#define WS_XQ_OFF   65536ull
#define WS_WT_OFF   8454144ull
#define WS_FULL_BYTES (8454144ull + 45088768ull)
#define WS_SMALL_BYTES 8454144ull

static __device__ __forceinline__ void llds16(const void* g, void* l) {
  __builtin_amdgcn_global_load_lds(
      reinterpret_cast<const uint32_t __attribute__((address_space(1)))*>(
          reinterpret_cast<uintptr_t>(g)),
      reinterpret_cast<uint32_t __attribute__((address_space(3)))*>(
          reinterpret_cast<uintptr_t>(l)),
      16, 0, 0);
}

// ---------------- kernel 1: per-block abs-max over x ----------------
__global__ __launch_bounds__(256) void absmax_kernel(const float* __restrict__ x,
                                                     float* __restrict__ part) {
  __shared__ float red[256];
  const int g = blockIdx.x * 256 + threadIdx.x;
  const float4* x4 = reinterpret_cast<const float4*>(x);
  float m = 0.f;
#pragma unroll
  for (int i = 0; i < 8; ++i) {
    float4 v = x4[(size_t)i * 262144 + g];
    m = fmaxf(m, fmaxf(fmaxf(fabsf(v.x), fabsf(v.y)),
                       fmaxf(fabsf(v.z), fabsf(v.w))));
  }
  red[threadIdx.x] = m;
  __syncthreads();
  for (int s = 128; s > 0; s >>= 1) {
    if (threadIdx.x < s) red[threadIdx.x] = fmaxf(red[threadIdx.x], red[threadIdx.x + s]);
    __syncthreads();
  }
  if (threadIdx.x == 0) part[blockIdx.x] = red[0];
}

// ---------------- kernel 2: finalize scales ----------------
__global__ __launch_bounds__(256) void finalize_scale(const float* __restrict__ part,
                                                      const float* __restrict__ y_scale,
                                                      float* __restrict__ scales) {
  __shared__ float red[256];
  const int t = threadIdx.x;
  float m = fmaxf(fmaxf(part[t], part[t + 256]), fmaxf(part[t + 512], part[t + 768]));
  red[t] = m;
  __syncthreads();
  for (int s = 128; s > 0; s >>= 1) {
    if (t < s) red[t] = fmaxf(red[t], red[t + s]);
    __syncthreads();
  }
  if (t == 0) {
    float xs = red[0] * (1.0f / 128.0f);  // exact (pow2)
    scales[0] = xs;
    scales[1] = xs * y_scale[0];
  }
}

// ---------------- kernel 3: quantize x -> int8 ----------------
__global__ __launch_bounds__(256) void quant_kernel(const float* __restrict__ x,
                                                    const float* __restrict__ scales,
                                                    signed char* __restrict__ xq) {
  const float s = scales[0];
  const size_t t = (size_t)blockIdx.x * 256 + threadIdx.x;
  const float4* x4 = reinterpret_cast<const float4*>(x) + t * 4;
  v4i o;
#pragma unroll
  for (int i = 0; i < 4; ++i) {
    float4 v = x4[i];
    int q0 = (int)rintf(v.x / s);  // matches np.round (half-to-even)
    int q1 = (int)rintf(v.y / s);
    int q2 = (int)rintf(v.z / s);
    int q3 = (int)rintf(v.w / s);
    q0 = max(-128, min(127, q0));
    q1 = max(-128, min(127, q1));
    q2 = max(-128, min(127, q2));
    q3 = max(-128, min(127, q3));
    o[i] = (q0 & 255) | ((q1 & 255) << 8) | ((q2 & 255) << 16) | ((q3 & 255) << 24);
  }
  *reinterpret_cast<v4i*>(xq + t * 16) = o;
}

// ---------------- kernel 4: transpose+pack w32[K,N] -> w_t int8[N,K] ----------------
__global__ __launch_bounds__(256) void transpose_pack(const int* __restrict__ w,
                                                      signed char* __restrict__ wt) {
  __shared__ int tile[64 * 65];
  const int t = threadIdx.x;
  const int n0 = blockIdx.x * 64;
  const int k0 = blockIdx.y * 64;
#pragma unroll
  for (int p = 0; p < 4; ++p) {
    const int id = p * 256 + t;
    const int r = id >> 4;
    const int c4 = id & 15;
    v4i v = *reinterpret_cast<const v4i*>(w + (size_t)(k0 + r) * N_DIM + n0 + c4 * 4);
    tile[r * 65 + c4 * 4 + 0] = v[0];
    tile[r * 65 + c4 * 4 + 1] = v[1];
    tile[r * 65 + c4 * 4 + 2] = v[2];
    tile[r * 65 + c4 * 4 + 3] = v[3];
  }
  __syncthreads();
  const int nl = t >> 2;
  const int kseg = t & 3;
  v4i o;
#pragma unroll
  for (int q = 0; q < 4; ++q) {
    const int kb = kseg * 16 + q * 4;
    int b0 = tile[(kb + 0) * 65 + nl] & 255;
    int b1 = tile[(kb + 1) * 65 + nl] & 255;
    int b2 = tile[(kb + 2) * 65 + nl] & 255;
    int b3 = tile[(kb + 3) * 65 + nl] & 255;
    o[q] = b0 | (b1 << 8) | (b2 << 16) | (b3 << 24);
  }
  *reinterpret_cast<v4i*>(wt + (size_t)(n0 + nl) * K_DIM + k0 + kseg * 16) = o;
}

// ---------------- kernel 5: int8 MFMA GEMM v5 (grid-efficiency first) ----------
// BM=BN=128, BK=64 bytes. 256 threads = 4 waves (2x2), wave-tile 64x64 via
// 4x4 frags of mfma_i32_16x16x64_i8 (R1-proven maps, R4-proven swizzle).
// Ring-3 LDS = 3 x 16KB = 48KB -> 3 blocks/CU (144KB), capacity 768 blocks.
// 1376 tiles / 768 = 1.79 rounds -> ~90% grid efficiency (vs 67% at 688/512).
// Depth-2 prefetch, vmcnt(4) once per K-tile (never 0 in main loop).
#define V5_TILE_B 16384           // A 128x64 (8KB) + B 128x64 (8KB)
#define V5_NT     (K_DIM / 64)    // 64 K-tiles

__global__ __launch_bounds__(256, 4) void gemm_i8_v5(
    const signed char* __restrict__ xq, const signed char* __restrict__ wt,
    const float* __restrict__ scales, const float* __restrict__ bias,
    float* __restrict__ y) {
  __shared__ __align__(16) signed char smem[3 * V5_TILE_B];  // 48 KB
  const int tid = threadIdx.x;

  // T1: bijective XCD swizzle (1376 blocks = 8 x 172), column-major grid
  // (16 m-tiles share each 512KB wt n-panel in L2).
  const int bid = blockIdx.x;
  const int swz = (bid & 7) * 172 + (bid >> 3);
  const int m0 = (swz & 15) * 128;
  const int n0 = (swz >> 4) * 128;

  // ---- staging map: thread -> (row = tid>>2, seg = tid&3) of a 64B row.
  // LDS dest linear; XOR involution seg' = seg ^ ((row>>1)&3) applied on the
  // GLOBAL source (both-sides rule). K-offsets and +64-row offsets preserve
  // (row>>1)&3 -> swizzle is k- and row-block-invariant.  [R4-proven, 0 confl]
  const int srow = tid >> 2;   // 0..63
  const int sseg = tid & 3;
  const int sgoff = (sseg ^ ((srow >> 1) & 3)) * 16;
  const signed char* gA = xq + (size_t)(m0 + srow) * K_DIM + sgoff;
  const signed char* gB = wt + (size_t)(n0 + srow) * K_DIM + sgoff;
  signed char* const ldA = smem + tid * 16;          // A: [0, 8192)
  signed char* const ldB = smem + 8192 + tid * 16;   // B: [8192, 16384)

#define STAGE(kt, soff)                                     \
  do {                                                      \
    const size_t ko_ = (size_t)(kt) * 64;                   \
    llds16(gA + ko_,                      ldA + (soff));    \
    llds16(gA + ko_ + (size_t)64 * K_DIM, ldA + (soff) + 4096); \
    llds16(gB + ko_,                      ldB + (soff));    \
    llds16(gB + ko_ + (size_t)64 * K_DIM, ldB + (soff) + 4096); \
  } while (0)

  // ---- fragment map (R1-proven lane rules): lane l -> row l&15 (+16*frag),
  // 16B chunk kc = l>>4; seg_phys = kc ^ ((row>>1)&3); frag row offsets are
  // multiples of 16 -> swizzle depends on l15 only.
  const int lane = tid & 63;
  const int wid = tid >> 6;
  const int wr = wid >> 1;   // 0..1 -> 64-row half
  const int wc = wid & 1;    // 0..1 -> 64-col half
  const int l15 = lane & 15;
  const int kc = lane >> 4;
  const int segoff = (kc ^ ((l15 >> 1) & 3)) * 16;
  const int offA = (wr * 64 + l15) * 64 + segoff;          // + m*1024
  const int offB = 8192 + (wc * 64 + l15) * 64 + segoff;   // + n*1024

  v4i acc[4][4] = {};

#define COMPUTE(roff)                                                        \
  do {                                                                       \
    const signed char* bp_ = smem + (roff);                                  \
    v4i a_[4], b_[4];                                                        \
    _Pragma("unroll")                                                        \
    for (int m_ = 0; m_ < 4; ++m_)                                           \
      a_[m_] = *reinterpret_cast<const v4i*>(bp_ + offA + m_ * 1024);        \
    _Pragma("unroll")                                                        \
    for (int n_ = 0; n_ < 4; ++n_)                                           \
      b_[n_] = *reinterpret_cast<const v4i*>(bp_ + offB + n_ * 1024);        \
    __builtin_amdgcn_s_setprio(1);                                           \
    _Pragma("unroll")                                                        \
    for (int m_ = 0; m_ < 4; ++m_)                                           \
      _Pragma("unroll")                                                      \
      for (int n_ = 0; n_ < 4; ++n_)                                         \
        acc[m_][n_] = __builtin_amdgcn_mfma_i32_16x16x64_i8(                 \
            a_[m_], b_[n_], acc[m_][n_], 0, 0, 0);                           \
    __builtin_amdgcn_s_setprio(0);                                           \
  } while (0)

// one main-loop iteration: stage tile kt2 (ring slot S), compute ring slot R,
// gate tile t+1 (outstanding t+1:4 + t+2:4 = 8 -> vmcnt(4), never 0).
#define ITER(R, S, kt2)                                     \
  do {                                                      \
    STAGE((kt2), (S));                                      \
    COMPUTE((R));                                           \
    asm volatile("s_waitcnt vmcnt(4)" ::: "memory");        \
    __builtin_amdgcn_s_barrier();                           \
  } while (0)

  // prologue: stage tiles 0,1 (8 loads in flight); retire tile 0 only.
  STAGE(0, 0);
  STAGE(1, V5_TILE_B);
  asm volatile("s_waitcnt vmcnt(4)" ::: "memory");
  __builtin_amdgcn_s_barrier();

  // main loop: iters t=0..61 (ring period 3, unrolled so offsets fold to
  // immediates). Iter t: read buf t%3, stage tile t+2 -> buf (t+2)%3.
  for (int t = 0; t < 60; t += 3) {
    ITER(0,              2 * V5_TILE_B, t + 2);
    ITER(V5_TILE_B,      0,             t + 3);
    ITER(2 * V5_TILE_B,  V5_TILE_B,     t + 4);
  }
  ITER(0,         2 * V5_TILE_B, 62);  // t=60
  ITER(V5_TILE_B, 0,             63);  // t=61
  // t=62: compute buf2; drain tile 63 (tail only vmcnt(0))
  COMPUTE(2 * V5_TILE_B);
  asm volatile("s_waitcnt vmcnt(0)" ::: "memory");
  __builtin_amdgcn_s_barrier();
  // t=63: final tile in buf0
  COMPUTE(0);

#undef STAGE
#undef COMPUTE
#undef ITER

  // epilogue: C/D 16x16 layout col=lane&15, row=(lane>>4)*4+reg (R1-proven)
  const float s = scales[1];
#pragma unroll
  for (int n = 0; n < 4; ++n) {
    const int col = n0 + wc * 64 + n * 16 + l15;
    const float bv = bias[col];
#pragma unroll
    for (int m = 0; m < 4; ++m) {
      const int r0 = m0 + wr * 64 + m * 16 + kc * 4;
#pragma unroll
      for (int j = 0; j < 4; ++j)
        y[(size_t)(r0 + j) * N_DIM + col] = (float)acc[m][n][j] * s + bv;
    }
  }
}

// ---------------- fallback (small ws): sdot4 LDS GEMM reading w32 ----------------
#if defined(__has_builtin)
#if __has_builtin(__builtin_amdgcn_sdot4)
#define HAVE_SDOT4 1
#endif
#endif

static __device__ __forceinline__ int dot4(int a, int b, int c) {
#ifdef HAVE_SDOT4
  return __builtin_amdgcn_sdot4(a, b, c, false);
#else
  c += (int)(signed char)(a) * (int)(signed char)(b);
  c += (int)(signed char)(a >> 8) * (int)(signed char)(b >> 8);
  c += (int)(signed char)(a >> 16) * (int)(signed char)(b >> 16);
  c += (int)(signed char)(a >> 24) * (int)(signed char)(b >> 24);
  return c;
#endif
}

__global__ __launch_bounds__(256) void gemm_fallback(
    const signed char* __restrict__ xq, const int* __restrict__ w,
    const float* __restrict__ scales, const float* __restrict__ bias,
    float* __restrict__ y) {
  __shared__ int lds_a[64 * 17];
  __shared__ int lds_b[64 * 17];
  const int t = threadIdx.x;
  const int m0 = blockIdx.y * 64;
  const int n0 = blockIdx.x * 64;
  const int my = (t >> 4) * 4;
  const int nx = (t & 15) * 4;
  int acc[4][4] = {};
  for (int kt = 0; kt < K_DIM / 64; ++kt) {
    const int k0 = kt * 64;
    {
      const int r = t >> 2, sg = t & 3;
      v4i v = *reinterpret_cast<const v4i*>(xq + (size_t)(m0 + r) * K_DIM + k0 + sg * 16);
      lds_a[r * 17 + sg * 4 + 0] = v[0];
      lds_a[r * 17 + sg * 4 + 1] = v[1];
      lds_a[r * 17 + sg * 4 + 2] = v[2];
      lds_a[r * 17 + sg * 4 + 3] = v[3];
    }
    {
      const int n = t & 63, bkk = (t >> 6) * 4;
#pragma unroll
      for (int q = 0; q < 4; ++q) {
        const int kk = bkk + q;
        int b0 = w[(size_t)(k0 + kk * 4 + 0) * N_DIM + n0 + n] & 255;
        int b1 = w[(size_t)(k0 + kk * 4 + 1) * N_DIM + n0 + n] & 255;
        int b2 = w[(size_t)(k0 + kk * 4 + 2) * N_DIM + n0 + n] & 255;
        int b3 = w[(size_t)(k0 + kk * 4 + 3) * N_DIM + n0 + n] & 255;
        lds_b[n * 17 + kk] = b0 | (b1 << 8) | (b2 << 16) | (b3 << 24);
      }
    }
    __syncthreads();
#pragma unroll
    for (int kk = 0; kk < 16; ++kk) {
      int a[4], b[4];
#pragma unroll
      for (int i = 0; i < 4; ++i) a[i] = lds_a[(my + i) * 17 + kk];
#pragma unroll
      for (int j = 0; j < 4; ++j) b[j] = lds_b[(nx + j) * 17 + kk];
#pragma unroll
      for (int i = 0; i < 4; ++i)
#pragma unroll
        for (int j = 0; j < 4; ++j) acc[i][j] = dot4(a[i], b[j], acc[i][j]);
    }
    __syncthreads();
  }
  const float s = scales[1];
#pragma unroll
  for (int i = 0; i < 4; ++i)
#pragma unroll
    for (int j = 0; j < 4; ++j)
      y[(size_t)(m0 + my + i) * N_DIM + n0 + nx + j] =
          (float)acc[i][j] * s + bias[n0 + nx + j];
}

// ---------------- launcher ----------------
extern "C" void kernel_launch(void* const* d_in, const int* in_sizes, int n_in,
                              void* d_out, int out_size, void* d_ws, size_t ws_size,
                              hipStream_t stream) {
  (void)in_sizes; (void)n_in; (void)out_size;
  const float* x = (const float*)d_in[0];
  const int* w = (const int*)d_in[1];  // int8 values stored as int32
  const float* bias = (const float*)d_in[2];
  const float* yscale = (const float*)d_in[3];
  float* y = (float*)d_out;
  char* ws = (char*)d_ws;
  float* scales = (float*)(ws);
  float* part = (float*)(ws + 1024);
  signed char* xq = (signed char*)(ws + WS_XQ_OFF);
  signed char* wt = (signed char*)(ws + WS_WT_OFF);

  if (ws_size < WS_SMALL_BYTES) return;

  absmax_kernel<<<1024, 256, 0, stream>>>(x, part);
  finalize_scale<<<1, 256, 0, stream>>>(part, yscale, scales);
  quant_kernel<<<2048, 256, 0, stream>>>(x, scales, xq);
  if (ws_size >= WS_FULL_BYTES) {
    transpose_pack<<<dim3(N_DIM / 64, K_DIM / 64), 256, 0, stream>>>(w, wt);
    gemm_i8_v5<<<(M_DIM / 128) * (N_DIM / 128), 256, 0, stream>>>(xq, wt, scales, bias, y);
  } else {
    gemm_fallback<<<dim3(N_DIM / 64, M_DIM / 64), 256, 0, stream>>>(xq, w, scales, bias, y);
  }
}

// Round 6
// 167.928 us; speedup vs baseline: 1.1112x; 1.1112x over previous
//
#include <hip/hip_runtime.h>
#include <stdint.h>

#define M_DIM 2048
#define K_DIM 4096
#define N_DIM 11008

typedef int v4i __attribute__((ext_vector_type(4)));

// ---------------- workspace layout ----------------
#define WS_XQ_OFF   65536ull
#define WS_WT_OFF   8454144ull
#define WS_FULL_BYTES (8454144ull + 45088768ull)
#define WS_SMALL_BYTES 8454144ull

static __device__ __forceinline__ void llds16(const void* g, void* l) {
  __builtin_amdgcn_global_load_lds(
      reinterpret_cast<const uint32_t __attribute__((address_space(1)))*>(
          reinterpret_cast<uintptr_t>(g)),
      reinterpret_cast<uint32_t __attribute__((address_space(3)))*>(
          reinterpret_cast<uintptr_t>(l)),
      16, 0, 0);
}

// ---------------- kernel 1: per-block abs-max over x ----------------
__global__ __launch_bounds__(256) void absmax_kernel(const float* __restrict__ x,
                                                     float* __restrict__ part) {
  __shared__ float red[256];
  const int g = blockIdx.x * 256 + threadIdx.x;
  const float4* x4 = reinterpret_cast<const float4*>(x);
  float m = 0.f;
#pragma unroll
  for (int i = 0; i < 8; ++i) {
    float4 v = x4[(size_t)i * 262144 + g];
    m = fmaxf(m, fmaxf(fmaxf(fabsf(v.x), fabsf(v.y)),
                       fmaxf(fabsf(v.z), fabsf(v.w))));
  }
  red[threadIdx.x] = m;
  __syncthreads();
  for (int s = 128; s > 0; s >>= 1) {
    if (threadIdx.x < s) red[threadIdx.x] = fmaxf(red[threadIdx.x], red[threadIdx.x + s]);
    __syncthreads();
  }
  if (threadIdx.x == 0) part[blockIdx.x] = red[0];
}

// ---------------- kernel 2: finalize scales ----------------
__global__ __launch_bounds__(256) void finalize_scale(const float* __restrict__ part,
                                                      const float* __restrict__ y_scale,
                                                      float* __restrict__ scales) {
  __shared__ float red[256];
  const int t = threadIdx.x;
  float m = fmaxf(fmaxf(part[t], part[t + 256]), fmaxf(part[t + 512], part[t + 768]));
  red[t] = m;
  __syncthreads();
  for (int s = 128; s > 0; s >>= 1) {
    if (t < s) red[t] = fmaxf(red[t], red[t + s]);
    __syncthreads();
  }
  if (t == 0) {
    float xs = red[0] * (1.0f / 128.0f);  // exact (pow2)
    scales[0] = xs;
    scales[1] = xs * y_scale[0];
  }
}

// ---------------- kernel 3: quantize x -> int8 ----------------
__global__ __launch_bounds__(256) void quant_kernel(const float* __restrict__ x,
                                                    const float* __restrict__ scales,
                                                    signed char* __restrict__ xq) {
  const float s = scales[0];
  const size_t t = (size_t)blockIdx.x * 256 + threadIdx.x;
  const float4* x4 = reinterpret_cast<const float4*>(x) + t * 4;
  v4i o;
#pragma unroll
  for (int i = 0; i < 4; ++i) {
    float4 v = x4[i];
    int q0 = (int)rintf(v.x / s);  // matches np.round (half-to-even)
    int q1 = (int)rintf(v.y / s);
    int q2 = (int)rintf(v.z / s);
    int q3 = (int)rintf(v.w / s);
    q0 = max(-128, min(127, q0));
    q1 = max(-128, min(127, q1));
    q2 = max(-128, min(127, q2));
    q3 = max(-128, min(127, q3));
    o[i] = (q0 & 255) | ((q1 & 255) << 8) | ((q2 & 255) << 16) | ((q3 & 255) << 24);
  }
  *reinterpret_cast<v4i*>(xq + t * 16) = o;
}

// ---------------- kernel 4: transpose+pack w32[K,N] -> w_t int8[N,K] ----------------
__global__ __launch_bounds__(256) void transpose_pack(const int* __restrict__ w,
                                                      signed char* __restrict__ wt) {
  __shared__ int tile[64 * 65];
  const int t = threadIdx.x;
  const int n0 = blockIdx.x * 64;
  const int k0 = blockIdx.y * 64;
#pragma unroll
  for (int p = 0; p < 4; ++p) {
    const int id = p * 256 + t;
    const int r = id >> 4;
    const int c4 = id & 15;
    v4i v = *reinterpret_cast<const v4i*>(w + (size_t)(k0 + r) * N_DIM + n0 + c4 * 4);
    tile[r * 65 + c4 * 4 + 0] = v[0];
    tile[r * 65 + c4 * 4 + 1] = v[1];
    tile[r * 65 + c4 * 4 + 2] = v[2];
    tile[r * 65 + c4 * 4 + 3] = v[3];
  }
  __syncthreads();
  const int nl = t >> 2;
  const int kseg = t & 3;
  v4i o;
#pragma unroll
  for (int q = 0; q < 4; ++q) {
    const int kb = kseg * 16 + q * 4;
    int b0 = tile[(kb + 0) * 65 + nl] & 255;
    int b1 = tile[(kb + 1) * 65 + nl] & 255;
    int b2 = tile[(kb + 2) * 65 + nl] & 255;
    int b3 = tile[(kb + 3) * 65 + nl] & 255;
    o[q] = b0 | (b1 << 8) | (b2 << 16) | (b3 << 24);
  }
  *reinterpret_cast<v4i*>(wt + (size_t)(n0 + nl) * K_DIM + k0 + kseg * 16) = o;
}

// ---------------- kernel 5: int8 MFMA GEMM v6 (wave-tile 64x128) ----------------
// BM=128, BN=256, BK=64 bytes. 256 threads = 4 waves (2M x 2N), wave-tile
// 64x128 via 4x8 frags of mfma_i32_16x16x64_i8. Geometry cuts LDS-read
// cycles/op by 1.33x vs R4's 64x64 (reads ~ Wm+Wn, ops ~ Wm*Wn).
// Ring-3 LDS = 3 x 24KB = 72KB -> 2 blocks/CU (R4-proven residency).
// Depth-2 prefetch, vmcnt(6) once per K-tile (never 0 in main loop).
#define V6_TILE_B 24576           // A 128x64 (8KB) + B 256x64 (16KB)
#define V6_NT     (K_DIM / 64)    // 64 K-tiles

__global__ __launch_bounds__(256, 2) void gemm_i8_v6(
    const signed char* __restrict__ xq, const signed char* __restrict__ wt,
    const float* __restrict__ scales, const float* __restrict__ bias,
    float* __restrict__ y) {
  __shared__ __align__(16) signed char smem[3 * V6_TILE_B];  // 72 KB
  const int tid = threadIdx.x;

  // T1: bijective XCD swizzle (688 blocks = 8 x 86), column-major grid
  // (16 m-tiles share each 1MB wt n-panel in L2).
  const int bid = blockIdx.x;
  const int swz = (bid & 7) * 86 + (bid >> 3);
  const int m0 = (swz & 15) * 128;
  const int n0 = (swz >> 4) * 256;

  // ---- staging map: thread -> (row = tid>>2, seg = tid&3) of a 64B row.
  // LDS dest linear; XOR involution seg' = seg ^ ((row>>1)&3) on the GLOBAL
  // source (both-sides rule). Row offsets (+64,+128,+192) and k-offsets
  // preserve (row>>1)&3 -> swizzle row-block- and k-invariant. [R4: 0 confl]
  const int srow = tid >> 2;   // 0..63
  const int sseg = tid & 3;
  const int sgoff = (sseg ^ ((srow >> 1) & 3)) * 16;
  const signed char* gA = xq + (size_t)(m0 + srow) * K_DIM + sgoff;
  const signed char* gB = wt + (size_t)(n0 + srow) * K_DIM + sgoff;
  signed char* const ldA = smem + tid * 16;          // A: [0, 8192)
  signed char* const ldB = smem + 8192 + tid * 16;   // B: [8192, 24576)

#define STAGE(kt, soff)                                                    \
  do {                                                                     \
    const size_t ko_ = (size_t)(kt) * 64;                                  \
    llds16(gA + ko_,                       ldA + (soff));                  \
    llds16(gA + ko_ + (size_t)64 * K_DIM,  ldA + (soff) + 4096);           \
    llds16(gB + ko_,                       ldB + (soff));                  \
    llds16(gB + ko_ + (size_t)64 * K_DIM,  ldB + (soff) + 4096);           \
    llds16(gB + ko_ + (size_t)128 * K_DIM, ldB + (soff) + 8192);           \
    llds16(gB + ko_ + (size_t)192 * K_DIM, ldB + (soff) + 12288);          \
  } while (0)

  // ---- fragment map (R1-proven lane rules): lane l -> row l&15 (+16*frag),
  // 16B chunk kc = l>>4; seg_phys = kc ^ ((row>>1)&3); frag row offsets are
  // multiples of 16 -> swizzle depends on l15 only.
  const int lane = tid & 63;
  const int wid = tid >> 6;
  const int wm = wid >> 1;   // 0..1 -> 64-row half of 128
  const int wn = wid & 1;    // 0..1 -> 128-col half of 256
  const int l15 = lane & 15;
  const int kc = lane >> 4;
  const int segoff = (kc ^ ((l15 >> 1) & 3)) * 16;
  const int offA = (wm * 64 + l15) * 64 + segoff;           // + m*1024
  const int offB = 8192 + (wn * 128 + l15) * 64 + segoff;   // + n*1024

  v4i acc[4][8] = {};

#define COMPUTE(roff)                                                        \
  do {                                                                       \
    const signed char* bp_ = smem + (roff);                                  \
    v4i a_[4], b_[8];                                                        \
    _Pragma("unroll")                                                        \
    for (int m_ = 0; m_ < 4; ++m_)                                           \
      a_[m_] = *reinterpret_cast<const v4i*>(bp_ + offA + m_ * 1024);        \
    _Pragma("unroll")                                                        \
    for (int n_ = 0; n_ < 8; ++n_)                                           \
      b_[n_] = *reinterpret_cast<const v4i*>(bp_ + offB + n_ * 1024);        \
    _Pragma("unroll")                                                        \
    for (int m_ = 0; m_ < 4; ++m_)                                           \
      _Pragma("unroll")                                                      \
      for (int n_ = 0; n_ < 8; ++n_)                                         \
        acc[m_][n_] = __builtin_amdgcn_mfma_i32_16x16x64_i8(                 \
            a_[m_], b_[n_], acc[m_][n_], 0, 0, 0);                           \
  } while (0)

  // prologue: stage tiles 0,1 (12 loads/thread in flight); retire tile 0.
  STAGE(0, 0);
  STAGE(1, V6_TILE_B);
  asm volatile("s_waitcnt vmcnt(6)" ::: "memory");
  __builtin_amdgcn_s_barrier();

  int rOff = 0;
  int sOff = 2 * V6_TILE_B;
  for (int t = 0; t < V6_NT - 2; ++t) {
    STAGE(t + 2, sOff);              // outstanding: t+1:6, t+2:6
    COMPUTE(rOff);                   // 12 ds_read_b128 + 32 MFMA
    asm volatile("s_waitcnt vmcnt(6)" ::: "memory");  // retire tile t+1
    __builtin_amdgcn_s_barrier();
    rOff = (rOff == 2 * V6_TILE_B) ? 0 : rOff + V6_TILE_B;
    sOff = (sOff == 2 * V6_TILE_B) ? 0 : sOff + V6_TILE_B;
  }
  // t = NT-2: no staging; drain remaining tile
  COMPUTE(rOff);
  asm volatile("s_waitcnt vmcnt(0)" ::: "memory");
  __builtin_amdgcn_s_barrier();
  rOff = (rOff == 2 * V6_TILE_B) ? 0 : rOff + V6_TILE_B;
  // t = NT-1: final tile
  COMPUTE(rOff);

#undef STAGE
#undef COMPUTE

  // epilogue: C/D 16x16 layout col=lane&15, row=(lane>>4)*4+reg (R1-proven)
  const float s = scales[1];
#pragma unroll
  for (int n = 0; n < 8; ++n) {
    const int col = n0 + wn * 128 + n * 16 + l15;
    const float bv = bias[col];
#pragma unroll
    for (int m = 0; m < 4; ++m) {
      const int r0 = m0 + wm * 64 + m * 16 + kc * 4;
#pragma unroll
      for (int j = 0; j < 4; ++j)
        y[(size_t)(r0 + j) * N_DIM + col] = (float)acc[m][n][j] * s + bv;
    }
  }
}

// ---------------- fallback (small ws): sdot4 LDS GEMM reading w32 ----------------
#if defined(__has_builtin)
#if __has_builtin(__builtin_amdgcn_sdot4)
#define HAVE_SDOT4 1
#endif
#endif

static __device__ __forceinline__ int dot4(int a, int b, int c) {
#ifdef HAVE_SDOT4
  return __builtin_amdgcn_sdot4(a, b, c, false);
#else
  c += (int)(signed char)(a) * (int)(signed char)(b);
  c += (int)(signed char)(a >> 8) * (int)(signed char)(b >> 8);
  c += (int)(signed char)(a >> 16) * (int)(signed char)(b >> 16);
  c += (int)(signed char)(a >> 24) * (int)(signed char)(b >> 24);
  return c;
#endif
}

__global__ __launch_bounds__(256) void gemm_fallback(
    const signed char* __restrict__ xq, const int* __restrict__ w,
    const float* __restrict__ scales, const float* __restrict__ bias,
    float* __restrict__ y) {
  __shared__ int lds_a[64 * 17];
  __shared__ int lds_b[64 * 17];
  const int t = threadIdx.x;
  const int m0 = blockIdx.y * 64;
  const int n0 = blockIdx.x * 64;
  const int my = (t >> 4) * 4;
  const int nx = (t & 15) * 4;
  int acc[4][4] = {};
  for (int kt = 0; kt < K_DIM / 64; ++kt) {
    const int k0 = kt * 64;
    {
      const int r = t >> 2, sg = t & 3;
      v4i v = *reinterpret_cast<const v4i*>(xq + (size_t)(m0 + r) * K_DIM + k0 + sg * 16);
      lds_a[r * 17 + sg * 4 + 0] = v[0];
      lds_a[r * 17 + sg * 4 + 1] = v[1];
      lds_a[r * 17 + sg * 4 + 2] = v[2];
      lds_a[r * 17 + sg * 4 + 3] = v[3];
    }
    {
      const int n = t & 63, bkk = (t >> 6) * 4;
#pragma unroll
      for (int q = 0; q < 4; ++q) {
        const int kk = bkk + q;
        int b0 = w[(size_t)(k0 + kk * 4 + 0) * N_DIM + n0 + n] & 255;
        int b1 = w[(size_t)(k0 + kk * 4 + 1) * N_DIM + n0 + n] & 255;
        int b2 = w[(size_t)(k0 + kk * 4 + 2) * N_DIM + n0 + n] & 255;
        int b3 = w[(size_t)(k0 + kk * 4 + 3) * N_DIM + n0 + n] & 255;
        lds_b[n * 17 + kk] = b0 | (b1 << 8) | (b2 << 16) | (b3 << 24);
      }
    }
    __syncthreads();
#pragma unroll
    for (int kk = 0; kk < 16; ++kk) {
      int a[4], b[4];
#pragma unroll
      for (int i = 0; i < 4; ++i) a[i] = lds_a[(my + i) * 17 + kk];
#pragma unroll
      for (int j = 0; j < 4; ++j) b[j] = lds_b[(nx + j) * 17 + kk];
#pragma unroll
      for (int i = 0; i < 4; ++i)
#pragma unroll
        for (int j = 0; j < 4; ++j) acc[i][j] = dot4(a[i], b[j], acc[i][j]);
    }
    __syncthreads();
  }
  const float s = scales[1];
#pragma unroll
  for (int i = 0; i < 4; ++i)
#pragma unroll
    for (int j = 0; j < 4; ++j)
      y[(size_t)(m0 + my + i) * N_DIM + n0 + nx + j] =
          (float)acc[i][j] * s + bias[n0 + nx + j];
}

// ---------------- launcher ----------------
extern "C" void kernel_launch(void* const* d_in, const int* in_sizes, int n_in,
                              void* d_out, int out_size, void* d_ws, size_t ws_size,
                              hipStream_t stream) {
  (void)in_sizes; (void)n_in; (void)out_size;
  const float* x = (const float*)d_in[0];
  const int* w = (const int*)d_in[1];  // int8 values stored as int32
  const float* bias = (const float*)d_in[2];
  const float* yscale = (const float*)d_in[3];
  float* y = (float*)d_out;
  char* ws = (char*)d_ws;
  float* scales = (float*)(ws);
  float* part = (float*)(ws + 1024);
  signed char* xq = (signed char*)(ws + WS_XQ_OFF);
  signed char* wt = (signed char*)(ws + WS_WT_OFF);

  if (ws_size < WS_SMALL_BYTES) return;

  absmax_kernel<<<1024, 256, 0, stream>>>(x, part);
  finalize_scale<<<1, 256, 0, stream>>>(part, yscale, scales);
  quant_kernel<<<2048, 256, 0, stream>>>(x, scales, xq);
  if (ws_size >= WS_FULL_BYTES) {
    transpose_pack<<<dim3(N_DIM / 64, K_DIM / 64), 256, 0, stream>>>(w, wt);
    gemm_i8_v6<<<(M_DIM / 128) * (N_DIM / 256), 256, 0, stream>>>(xq, wt, scales, bias, y);
  } else {
    gemm_fallback<<<dim3(N_DIM / 64, M_DIM / 64), 256, 0, stream>>>(xq, w, scales, bias, y);
  }
}